// Round 1
// baseline (85.361 us; speedup 1.0000x reference)
//
#include <hip/hip_runtime.h>

// ---- problem constants ----
#define BATCH   16384
#define NDENSE  64
#define HIDDEN  256
#define NOUT    256
#define MROWS   64     // rows per block -> grid 256 = 1 block/CU
#define NTILES  4      // 4 M-tiles of 16 rows
#define LDH     264    // hA row stride (elements); 528B stride, b128 reads 2-way (free)
#define LDOH    104    // one-hot row stride (elements)

typedef unsigned short u16;
typedef __attribute__((ext_vector_type(8))) unsigned short us8;
typedef __attribute__((ext_vector_type(8))) __bf16 bf16x8;
typedef __attribute__((ext_vector_type(4))) float f32x4;

__device__ __forceinline__ u16 f2bf(float x) {
    unsigned u = __builtin_bit_cast(unsigned, x);
    return (u16)((u + 0x7FFFu + ((u >> 16) & 1u)) >> 16);
}

// ---------------- prep: pack B matrices in MFMA-fragment order ----------------
// B1P: 80 frags (f = nidx*5+ks, nidx=0..15, ks=0..4), each 64 lanes x 8 bf16:
//   n = nidx*16+(lane&15); k = ks*32+(lane>>4)*8+e;  k<64 -> W1[k][n];
//   64<=k<144 -> W1[offs[j]+v][n]; k==144 -> b1[n]; else 0.
// W2P: 128 frags (f = nidx*8+ks): W2[k][n], k = ks*32+(lane>>4)*8+e.
__global__ __launch_bounds__(256) void prep_kernel(
    const float* __restrict__ W1, const float* __restrict__ b1,
    const float* __restrict__ W2,
    u16* __restrict__ B1P, u16* __restrict__ W2P) {
    const int g = blockIdx.x * 256 + threadIdx.x;
    const int offs[8] = {64, 1064, 1564, 1764, 1864, 1914, 1964, 1984};
    if (g < 5120) {                       // B1P
        const int f = g >> 6, lane = g & 63;
        const int ks = f % 5, nidx = f / 5;
        const int n = nidx * 16 + (lane & 15);
        const int kb = ks * 32 + (lane >> 4) * 8;
        us8 v;
#pragma unroll
        for (int e = 0; e < 8; ++e) {
            const int k = kb + e;
            float val;
            if (k < 64) {
                val = W1[k * HIDDEN + n];
            } else if (k < 144) {
                const int t = k - 64, j = t / 10, vv = t - 10 * j;
                val = W1[(offs[j] + vv) * HIDDEN + n];
            } else if (k == 144) {
                val = b1[n];
            } else {
                val = 0.0f;
            }
            v[e] = f2bf(val);
        }
        *(us8*)&B1P[f * 512 + lane * 8] = v;
    } else if (g < 13312) {               // W2P
        const int g2 = g - 5120;
        const int f = g2 >> 6, lane = g2 & 63;
        const int ks = f & 7, nidx = f >> 3;
        const int n = nidx * 16 + (lane & 15);
        const int kb = ks * 32 + (lane >> 4) * 8;
        us8 v;
#pragma unroll
        for (int e = 0; e < 8; ++e) v[e] = f2bf(W2[(kb + e) * NOUT + n]);
        *(us8*)&W2P[f * 512 + lane * 8] = v;
    }
}

// ------- fused: 64 rows/block, 1024 threads (16 waves x 16-col strips) -------
// 4 waves/SIMD (vs 2 before): __launch_bounds__(1024,4) caps VGPR at 128,
// so W2 fragments are JIT-pipelined in phase B instead of preloaded.
__global__ __launch_bounds__(1024, 4) void fused_kernel(
    const float* __restrict__ dense, const int* __restrict__ sparse,
    const u16* __restrict__ B1P, const u16* __restrict__ W2P,
    const float* __restrict__ b2, float* __restrict__ out) {
    __shared__ __align__(16) u16 hA[MROWS * LDH];   // 33.8 KB
    __shared__ __align__(16) u16 oh[MROWS * LDOH];  // 13.3 KB (all 64 rows)

    const int tid  = threadIdx.x;
    const int wv   = tid >> 6;          // 0..15 -> col strip [16wv, 16wv+16)
    const int lane = tid & 63;
    const int quad = lane >> 4;
    const int l16  = lane & 15;
    const int m0   = blockIdx.x * MROWS;

    // ---- issue loads in dependency order: sparse (oh scatter), dense, B1 ----
    int ohidx = 0;
    if (tid < MROWS * 8) ohidx = sparse[m0 * 8 + tid];   // (row tid>>3, feat tid&7)

    bf16x8 adF[NTILES][2];               // dense A-frags, global -> reg
#pragma unroll
    for (int t = 0; t < NTILES; ++t) {
        const float* p = &dense[(m0 + t * 16 + l16) * NDENSE + quad * 8];
        const f32x4 d0 = *(const f32x4*)p;
        const f32x4 d1 = *(const f32x4*)(p + 4);
        const f32x4 d2 = *(const f32x4*)(p + 32);
        const f32x4 d3 = *(const f32x4*)(p + 36);
        us8 a0, a1;
#pragma unroll
        for (int e = 0; e < 4; ++e) {
            a0[e] = f2bf(d0[e]); a0[e + 4] = f2bf(d1[e]);
            a1[e] = f2bf(d2[e]); a1[e + 4] = f2bf(d3[e]);
        }
        adF[t][0] = __builtin_bit_cast(bf16x8, a0);
        adF[t][1] = __builtin_bit_cast(bf16x8, a1);
    }

    us8 bf1[5];                          // B1 frags for this wave's 16 cols
#pragma unroll
    for (int ks = 0; ks < 5; ++ks)
        bf1[ks] = *(const us8*)&B1P[(wv * 5 + ks) * 512 + lane * 8];

    const float b2v = b2[wv * 16 + l16];

    // ---- build one-hot tile for ALL 64 rows: zero cols [0,96) then set ----
    const us8 zer = {0, 0, 0, 0, 0, 0, 0, 0};
    if (tid < MROWS * 12)                // 768 chunks = 64 rows x 12
        *(us8*)&oh[(tid / 12) * LDOH + (tid % 12) * 8] = zer;
    __syncthreads();
    if (tid < MROWS * 8)
        oh[(tid >> 3) * LDOH + 10 * (tid & 7) + ohidx] = 0x3F80;  // bf16 1.0
    if (tid < MROWS) oh[tid * LDOH + 80] = 0x3F80;                // bias col (k=144)
    __syncthreads();

    // ---- phase A: h = relu([dense|onehot|bias] @ B1) -> LDS ----
#pragma unroll
    for (int t = 0; t < NTILES; ++t) {
        f32x4 acc = {};
        acc = __builtin_amdgcn_mfma_f32_16x16x32_bf16(
            adF[t][0], __builtin_bit_cast(bf16x8, bf1[0]), acc, 0, 0, 0);
        acc = __builtin_amdgcn_mfma_f32_16x16x32_bf16(
            adF[t][1], __builtin_bit_cast(bf16x8, bf1[1]), acc, 0, 0, 0);
#pragma unroll
        for (int ks = 2; ks < 5; ++ks) {
            const bf16x8 af = *(const bf16x8*)&oh[(t * 16 + l16) * LDOH +
                                                  (ks - 2) * 32 + quad * 8];
            acc = __builtin_amdgcn_mfma_f32_16x16x32_bf16(
                af, __builtin_bit_cast(bf16x8, bf1[ks]), acc, 0, 0, 0);
        }
        // C/D layout: col = l16, row = quad*4+r
#pragma unroll
        for (int r = 0; r < 4; ++r)
            hA[(t * 16 + quad * 4 + r) * LDH + wv * 16 + l16] =
                f2bf(fmaxf(acc[r], 0.0f));
    }

    // ---- phase B: out = h @ W2 + b2, W2 frags JIT with prefetch distance 2 ----
    us8 bw[8];
    bw[0] = *(const us8*)&W2P[(wv * 8 + 0) * 512 + lane * 8];
    bw[1] = *(const us8*)&W2P[(wv * 8 + 1) * 512 + lane * 8];
    __syncthreads();

    f32x4 accB[NTILES] = {};
#pragma unroll
    for (int ks = 0; ks < 8; ++ks) {
        if (ks < 6)
            bw[ks + 2] = *(const us8*)&W2P[(wv * 8 + ks + 2) * 512 + lane * 8];
#pragma unroll
        for (int t = 0; t < NTILES; ++t) {
            const bf16x8 af = *(const bf16x8*)&hA[(t * 16 + l16) * LDH +
                                                  ks * 32 + quad * 8];
            accB[t] = __builtin_amdgcn_mfma_f32_16x16x32_bf16(
                af, __builtin_bit_cast(bf16x8, bw[ks]), accB[t], 0, 0, 0);
        }
    }

#pragma unroll
    for (int t = 0; t < NTILES; ++t) {
        const int col = wv * 16 + l16;
#pragma unroll
        for (int r = 0; r < 4; ++r)
            out[(m0 + t * 16 + quad * 4 + r) * NOUT + col] = accB[t][r] + b2v;
    }
}

extern "C" void kernel_launch(void* const* d_in, const int* in_sizes, int n_in,
                              void* d_out, int out_size, void* d_ws, size_t ws_size,
                              hipStream_t stream) {
    (void)in_sizes; (void)n_in; (void)out_size; (void)ws_size;
    const float* dense  = (const float*)d_in[0];
    const int*   sparse = (const int*)d_in[1];
    const float* W1     = (const float*)d_in[2];
    const float* b1     = (const float*)d_in[3];
    const float* W2     = (const float*)d_in[4];
    const float* b2     = (const float*)d_in[5];
    float* out = (float*)d_out;

    u16* B1P = (u16*)d_ws;                 // 80 frags * 1KB  = 80 KB
    u16* W2P = B1P + 80 * 512;             // 128 frags * 1KB = 128 KB

    hipLaunchKernelGGL(prep_kernel, dim3(52), dim3(256), 0, stream,
                       W1, b1, W2, B1P, W2P);
    hipLaunchKernelGGL(fused_kernel, dim3(BATCH / MROWS), dim3(1024), 0, stream,
                       dense, sparse, B1P, W2P, b2, out);
}

// Round 2
// 80.476 us; speedup vs baseline: 1.0607x; 1.0607x over previous
//
#include <hip/hip_runtime.h>

// ---- problem constants ----
#define BATCH   16384
#define NDENSE  64
#define HIDDEN  256
#define NOUT    256
#define MROWS   64     // rows per block -> grid 256 = 1 block/CU
#define NTILES  4      // 4 M-tiles of 16 rows
#define LDH     264    // hA row stride (elements); 528B/16 ok; bank stride 132%32=4
#define LDOH    104    // one-hot row stride (elements); 208B/16 ok

typedef unsigned short u16;
typedef __attribute__((ext_vector_type(8))) unsigned short us8;
typedef __attribute__((ext_vector_type(8))) __bf16 bf16x8;
typedef __attribute__((ext_vector_type(4))) float f32x4;

__device__ __forceinline__ u16 f2bf(float x) {
    unsigned u = __builtin_bit_cast(unsigned, x);
    return (u16)((u + 0x7FFFu + ((u >> 16) & 1u)) >> 16);
}

// ---- single fused kernel: weight fragments gathered in-kernel (no prep) ----
// 64 rows/block, 512 threads (8 waves x 32-col strips), grid 256 = 1 block/CU.
// B1 frag (ks,ni): lane holds [k = ks*32+quad*8+e][n = (wv*2+ni)*16+l16] of the
// implicit 160x256 first-layer matrix: k<64 -> W1 dense rows; 64<=k<144 ->
// one-hot rows W1[offs[j]+v] (via LDS LUT); k==144 -> b1; k>144 -> 0.
// W2 frag (ks,ni): W2[k][n], k = ks*32+quad*8+e.
__global__ __launch_bounds__(512, 2) void fused_kernel(
    const float* __restrict__ dense, const int* __restrict__ sparse,
    const float* __restrict__ W1, const float* __restrict__ b1,
    const float* __restrict__ W2, const float* __restrict__ b2,
    float* __restrict__ out) {
    __shared__ __align__(16) u16 hA[MROWS * LDH];   // 33.8 KB
    __shared__ __align__(16) u16 oh[MROWS * LDOH];  // 13.3 KB (all 64 rows)
    __shared__ int rows_lut[80];                    // one-hot k -> W1 row offset

    const int tid  = threadIdx.x;
    const int wv   = tid >> 6;          // 0..7 -> col strip [32wv, 32wv+32)
    const int lane = tid & 63;
    const int quad = lane >> 4;
    const int l16  = lane & 15;
    const int m0   = blockIdx.x * MROWS;

    // ---- longest-latency loads first: sparse (gates oh scatter), dense ----
    const int ohidx = sparse[m0 * 8 + tid];          // (row tid>>3, feat tid&7)

    bf16x8 adF[NTILES][2];               // dense A-frags, global -> reg
#pragma unroll
    for (int t = 0; t < NTILES; ++t) {
        const float* p = &dense[(m0 + t * 16 + l16) * NDENSE + quad * 8];
        const f32x4 d0 = *(const f32x4*)p;
        const f32x4 d1 = *(const f32x4*)(p + 4);
        const f32x4 d2 = *(const f32x4*)(p + 32);
        const f32x4 d3 = *(const f32x4*)(p + 36);
        us8 a0, a1;
#pragma unroll
        for (int e = 0; e < 4; ++e) {
            a0[e] = f2bf(d0[e]); a0[e + 4] = f2bf(d1[e]);
            a1[e] = f2bf(d2[e]); a1[e + 4] = f2bf(d3[e]);
        }
        adF[t][0] = __builtin_bit_cast(bf16x8, a0);
        adF[t][1] = __builtin_bit_cast(bf16x8, a1);
    }

    // ---- one-hot row LUT (select chain, no runtime-indexed local array) ----
    if (tid < 80) {
        const int j = tid / 10, v = tid - 10 * j;
        const int base = (j == 0) ? 64   : (j == 1) ? 1064 : (j == 2) ? 1564
                       : (j == 3) ? 1764 : (j == 4) ? 1864 : (j == 5) ? 1914
                       : (j == 6) ? 1964 : 1984;
        rows_lut[tid] = (base + v) * HIDDEN;         // element offset into W1
    }

    // ---- zero one-hot tile cols [0,96) for all 64 rows ----
    const us8 zer = {0, 0, 0, 0, 0, 0, 0, 0};
#pragma unroll
    for (int i = 0; i < 2; ++i) {
        const int c = tid + i * 512;                 // 768 chunks = 64 rows x 12
        if (c < MROWS * 12)
            *(us8*)&oh[(c / 12) * LDOH + (c % 12) * 8] = zer;
    }
    __syncthreads();                                 // lut ready + oh zeroed
    oh[(tid >> 3) * LDOH + 10 * (tid & 7) + ohidx] = 0x3F80;  // bf16 1.0
    if (tid < MROWS) oh[tid * LDOH + 80] = 0x3F80;            // bias col (k=144)

    // ---- gather weight fragments straight from W1/b1/W2 (L2-resident) ----
    const int n0 = (wv * 2) * 16 + l16;
    const int n1 = n0 + 16;

    bf16x8 bf1[5][2];
#pragma unroll
    for (int ks = 0; ks < 5; ++ks) {
#pragma unroll
        for (int e = 0; e < 8; ++e) {
            const int k = ks * 32 + quad * 8 + e;
            float v0, v1;
            if (ks < 2) {                            // k < 64: dense rows
                v0 = W1[k * HIDDEN + n0];
                v1 = W1[k * HIDDEN + n1];
            } else if (ks < 4) {                     // 64 <= k < 128: one-hot
                const int roff = rows_lut[k - 64];
                v0 = W1[roff + n0];
                v1 = W1[roff + n1];
            } else {                                 // ks == 4: mixed by quad
                if (quad < 2) {                      // k in [128,144)
                    const int roff = rows_lut[k - 64];
                    v0 = W1[roff + n0];
                    v1 = W1[roff + n1];
                } else if (quad == 2 && e == 0) {    // k == 144: bias row
                    v0 = b1[n0];
                    v1 = b1[n1];
                } else {                             // k > 144: zero pad
                    v0 = 0.0f;
                    v1 = 0.0f;
                }
            }
            bf1[ks][0][e] = (__bf16)v0;              // compiler packs cvt_pk
            bf1[ks][1][e] = (__bf16)v1;
        }
    }

    bf16x8 bw[8][2];
#pragma unroll
    for (int ks = 0; ks < 8; ++ks) {
#pragma unroll
        for (int e = 0; e < 8; ++e) {
            const int kr = (ks * 32 + quad * 8 + e) * NOUT;
            bw[ks][0][e] = (__bf16)W2[kr + n0];
            bw[ks][1][e] = (__bf16)W2[kr + n1];
        }
    }

    float b2v[2];
#pragma unroll
    for (int ni = 0; ni < 2; ++ni) b2v[ni] = b2[wv * 32 + ni * 16 + l16];

    __syncthreads();                                 // oh scatter visible

    // ---- phase A: h = relu([dense|onehot|bias] @ B1) -> LDS ----
#pragma unroll
    for (int t = 0; t < NTILES; ++t) {
        f32x4 acc[2] = {};
#pragma unroll
        for (int ni = 0; ni < 2; ++ni) {
            acc[ni] = __builtin_amdgcn_mfma_f32_16x16x32_bf16(
                adF[t][0], bf1[0][ni], acc[ni], 0, 0, 0);
            acc[ni] = __builtin_amdgcn_mfma_f32_16x16x32_bf16(
                adF[t][1], bf1[1][ni], acc[ni], 0, 0, 0);
        }
#pragma unroll
        for (int ks = 2; ks < 5; ++ks) {
            const bf16x8 af = *(const bf16x8*)&oh[(t * 16 + l16) * LDOH +
                                                  (ks - 2) * 32 + quad * 8];
#pragma unroll
            for (int ni = 0; ni < 2; ++ni)
                acc[ni] = __builtin_amdgcn_mfma_f32_16x16x32_bf16(
                    af, bf1[ks][ni], acc[ni], 0, 0, 0);
        }
        // C/D layout: col = l16, row = quad*4+r
#pragma unroll
        for (int ni = 0; ni < 2; ++ni)
#pragma unroll
            for (int r = 0; r < 4; ++r)
                hA[(t * 16 + quad * 4 + r) * LDH + wv * 32 + ni * 16 + l16] =
                    f2bf(fmaxf(acc[ni][r], 0.0f));
    }
    __syncthreads();

    // ---- phase B: out = h @ W2 + b2 ----
#pragma unroll
    for (int t = 0; t < NTILES; ++t) {
        f32x4 acc[2] = {};
#pragma unroll
        for (int ks = 0; ks < 8; ++ks) {
            const bf16x8 af = *(const bf16x8*)&hA[(t * 16 + l16) * LDH +
                                                  ks * 32 + quad * 8];
#pragma unroll
            for (int ni = 0; ni < 2; ++ni)
                acc[ni] = __builtin_amdgcn_mfma_f32_16x16x32_bf16(
                    af, bw[ks][ni], acc[ni], 0, 0, 0);
        }
#pragma unroll
        for (int ni = 0; ni < 2; ++ni) {
            const int col = wv * 32 + ni * 16 + l16;
#pragma unroll
            for (int r = 0; r < 4; ++r)
                out[(m0 + t * 16 + quad * 4 + r) * NOUT + col] = acc[ni][r] + b2v[ni];
        }
    }
}

extern "C" void kernel_launch(void* const* d_in, const int* in_sizes, int n_in,
                              void* d_out, int out_size, void* d_ws, size_t ws_size,
                              hipStream_t stream) {
    (void)in_sizes; (void)n_in; (void)out_size; (void)d_ws; (void)ws_size;
    const float* dense  = (const float*)d_in[0];
    const int*   sparse = (const int*)d_in[1];
    const float* W1     = (const float*)d_in[2];
    const float* b1     = (const float*)d_in[3];
    const float* W2     = (const float*)d_in[4];
    const float* b2     = (const float*)d_in[5];
    float* out = (float*)d_out;

    hipLaunchKernelGGL(fused_kernel, dim3(BATCH / MROWS), dim3(512), 0, stream,
                       dense, sparse, W1, b1, W2, b2, out);
}